// Round 2
// baseline (1101.225 us; speedup 1.0000x reference)
//
#include <hip/hip_runtime.h>

#define EPS 1e-6f

// DPP helper: v += v rotated by CTRL within each 16-lane row (row_ror:n = 0x120+n)
template <int CTRL>
__device__ __forceinline__ float dpp_add(float v) {
  int moved = __builtin_amdgcn_update_dpp(0, __float_as_int(v), CTRL, 0xF, 0xF, false);
  return v + __int_as_float(moved);
}

// ---------------------------------------------------------------------------
// Kernel A: P[b,n,r] = sum_d x[b,n,d] * bases[b,d,r]
// grid 256 = 16 b x 16 grp (32 rows/WG); block 512 = 8 waves:
//   wave w -> d-half h = w>>2, row-group rg = w&3 (8 rows), so the 4096-d
//   reduction is split across 2 waves -> 8 waves/CU instead of 4.
// Two 40KB LDS buffers stage the two halves' bases chunks independently.
// Cross-half combine via LDS; optional fused softmax writes coef.
// Blocks 0..15 also zero CtC for this iteration's fused coef-gram.
// ---------------------------------------------------------------------------
__global__ __launch_bounds__(512) void kernelA(
    const float* __restrict__ x, const float* __restrict__ bases,
    float* __restrict__ P, float* __restrict__ coef,
    float* __restrict__ CtC, int do_softmax)
{
  __shared__ __align__(16) float lb[20480];  // 2 buffers x 512 rows x stride 20 (80 KB)
  const int tid = threadIdx.x;
  if (blockIdx.x < 16 && tid < 256) CtC[blockIdx.x * 256 + tid] = 0.0f;
  const int b = blockIdx.x >> 4;
  const int grp = blockIdx.x & 15;
  const int w = tid >> 6;
  const int lane = tid & 63;
  const int h = w >> 2;   // d-half
  const int rg = w & 3;   // row group
  const int n0 = grp * 32 + rg * 8;
  const float* __restrict__ xp = x + ((size_t)(b * 512 + n0)) * 4096 + h * 2048;
  const float4* __restrict__ srcf4 = (const float4*)(bases + ((size_t)b) * 4096 * 16);

  float acc[8][16];
#pragma unroll
  for (int i = 0; i < 8; ++i)
#pragma unroll
    for (int r = 0; r < 16; ++r) acc[i][r] = 0.0f;

  for (int c = 0; c < 4; ++c) {
    // stage chunk c (half 0 -> buf 0) and chunk c+4 (half 1 -> buf 1)
#pragma unroll
    for (int k = 0; k < 8; ++k) {
      int idx = k * 512 + tid;            // 0..4095 float4
      int buf = idx >> 11;                // 0: chunk c, 1: chunk c+4
      int rem = idx & 2047;
      int dl = rem >> 2, q = rem & 3;
      int cg = c + buf * 4;
      *(float4*)(&lb[buf * 10240 + dl * 20 + q * 4]) = srcf4[(cg * 512 + dl) * 4 + q];
    }
    __syncthreads();
    const float* __restrict__ lbh = lb + h * 10240;
    const float* __restrict__ xpc = xp + c * 512;
#pragma unroll
    for (int j = 0; j < 8; ++j) {
      const int dl = j * 64 + lane;
      float xv[8];
#pragma unroll
      for (int i = 0; i < 8; ++i) xv[i] = xpc[(size_t)i * 4096 + dl];
      const float* row = &lbh[dl * 20];
#pragma unroll
      for (int q = 0; q < 4; ++q) {
        float4 bv = *(const float4*)(row + q * 4);
#pragma unroll
        for (int i = 0; i < 8; ++i) {
          acc[i][q * 4 + 0] = fmaf(xv[i], bv.x, acc[i][q * 4 + 0]);
          acc[i][q * 4 + 1] = fmaf(xv[i], bv.y, acc[i][q * 4 + 1]);
          acc[i][q * 4 + 2] = fmaf(xv[i], bv.z, acc[i][q * 4 + 2]);
          acc[i][q * 4 + 3] = fmaf(xv[i], bv.w, acc[i][q * 4 + 3]);
        }
      }
    }
    __syncthreads();
  }

  // lane-reduce each acc[i][r] across 64 lanes
#pragma unroll
  for (int i = 0; i < 8; ++i)
#pragma unroll
    for (int r = 0; r < 16; ++r) {
      float v = acc[i][r];
      v = dpp_add<0x121>(v);
      v = dpp_add<0x122>(v);
      v = dpp_add<0x124>(v);
      v = dpp_add<0x128>(v);
      v += __shfl_xor(v, 16, 64);
      v += __shfl_xor(v, 32, 64);
      acc[i][r] = v;
    }

  // cross-half combine via LDS (reuse lb; all compute done, last op was sync)
  if (lane == 0) {
#pragma unroll
    for (int i = 0; i < 8; ++i)
#pragma unroll
      for (int r = 0; r < 16; ++r) lb[(h * 4 + rg) * 128 + i * 16 + r] = acc[i][r];
  }
  __syncthreads();
  {
    const int row = tid >> 4;   // 0..31
    const int r = tid & 15;
    const int prg = row >> 3, pi = row & 7;
    float p = lb[(prg)*128 + pi * 16 + r] + lb[(4 + prg) * 128 + pi * 16 + r];
    P[((size_t)(b * 512 + grp * 32 + row)) * 16 + r] = p;
    if (do_softmax) {
      lb[1024 + tid] = p;
      __syncthreads();
      if (tid < 32) {
        const float* pf = &lb[1024 + tid * 16];
        float m = pf[0];
#pragma unroll
        for (int rr = 1; rr < 16; ++rr) m = fmaxf(m, pf[rr]);
        float e[16];
        float s = 0.0f;
#pragma unroll
        for (int rr = 0; rr < 16; ++rr) { e[rr] = __expf(100.0f * (pf[rr] - m)); s += e[rr]; }
        float inv = 1.0f / s;
        float* __restrict__ crow = coef + ((size_t)(b * 512 + grp * 32 + tid)) * 16;
#pragma unroll
        for (int rr = 0; rr < 16; ++rr) crow[rr] = e[rr] * inv;
      }
    }
  }
}

// ---------------------------------------------------------------------------
// Standalone gram (used once for BtB0): out[b,s*16+r] += sum_l M[.,r]*M[.,s]
// ---------------------------------------------------------------------------
__global__ __launch_bounds__(256) void kernelGram(
    const float* __restrict__ M, float* __restrict__ out, int L)
{
  __shared__ __align__(16) float sm[256 * 20];
  __shared__ __align__(16) float part[4 * 272];
  const int tid = threadIdx.x;
  const int b = blockIdx.y;
  const int sl = blockIdx.x;
  const float4* __restrict__ src = (const float4*)(M + ((size_t)b * L + (size_t)sl * 256) * 16);
#pragma unroll
  for (int k = 0; k < 4; ++k) {
    int idx = k * 256 + tid;
    int row = idx >> 2, q = idx & 3;
    *(float4*)(&sm[row * 20 + q * 4]) = src[idx];
  }
  __syncthreads();
  const int rq = tid & 3;
  const int s = (tid >> 2) & 15;
  const int g = tid >> 6;
  float a0 = 0.f, a1 = 0.f, a2 = 0.f, a3 = 0.f;
#pragma unroll 4
  for (int l = g * 64; l < g * 64 + 64; ++l) {
    float4 bv = *(const float4*)(&sm[l * 20 + rq * 4]);
    float cs = sm[l * 20 + s];
    a0 = fmaf(cs, bv.x, a0);
    a1 = fmaf(cs, bv.y, a1);
    a2 = fmaf(cs, bv.z, a2);
    a3 = fmaf(cs, bv.w, a3);
  }
  *(float4*)(&part[g * 272 + s * 16 + rq * 4]) = make_float4(a0, a1, a2, a3);
  __syncthreads();
  float v = part[0 * 272 + tid] + part[1 * 272 + tid] + part[2 * 272 + tid] + part[3 * 272 + tid];
  atomicAdd(out + b * 256 + tid, v);
}

// ---------------------------------------------------------------------------
// Coef update + fused CtC gram: coef *= P / (coef BtB + eps); CtC += gram(coef')
// grid 32 (2 blocks/batch); block 256 (thread = one n row). Also zeros BtBz.
// ---------------------------------------------------------------------------
__global__ __launch_bounds__(256) void kernelCU(
    float* __restrict__ coef, const float* __restrict__ P,
    const float* __restrict__ BtBr, float* __restrict__ BtBz,
    float* __restrict__ CtCadd)
{
  __shared__ __align__(16) float sm[256 * 20 + 4 * 272];
  const int tid = threadIdx.x;
  BtBz[blockIdx.x * 128 + (tid & 127)] = 0.0f;
  const int b = blockIdx.x >> 1;
  const int n = ((blockIdx.x & 1) << 8) + tid;
  float* __restrict__ crow = coef + ((size_t)(b * 512 + n)) * 16;
  const float* __restrict__ prow = P + ((size_t)(b * 512 + n)) * 16;
  const float* __restrict__ btb = BtBr + b * 256;
  float cv[16], den[16];
#pragma unroll
  for (int r = 0; r < 16; ++r) cv[r] = crow[r];
#pragma unroll
  for (int r = 0; r < 16; ++r) den[r] = 0.f;
#pragma unroll
  for (int s2 = 0; s2 < 16; ++s2) {
    const float bs = cv[s2];
#pragma unroll
    for (int r = 0; r < 16; ++r) den[r] = fmaf(bs, btb[s2 * 16 + r], den[r]);
  }
#pragma unroll
  for (int r = 0; r < 16; ++r) {
    float cn = cv[r] * prow[r] / (den[r] + EPS);
    crow[r] = cn;
    sm[tid * 20 + r] = cn;
  }
  __syncthreads();
  const int rq = tid & 3;
  const int s = (tid >> 2) & 15;
  const int g = tid >> 6;
  float a0 = 0.f, a1 = 0.f, a2 = 0.f, a3 = 0.f;
#pragma unroll 4
  for (int l = g * 64; l < g * 64 + 64; ++l) {
    float4 bv = *(const float4*)(&sm[l * 20 + rq * 4]);
    float cs = sm[l * 20 + s];
    a0 = fmaf(cs, bv.x, a0);
    a1 = fmaf(cs, bv.y, a1);
    a2 = fmaf(cs, bv.z, a2);
    a3 = fmaf(cs, bv.w, a3);
  }
  float* part = sm + 5120;
  *(float4*)(&part[g * 272 + s * 16 + rq * 4]) = make_float4(a0, a1, a2, a3);
  __syncthreads();
  float v = part[0 * 272 + tid] + part[1 * 272 + tid] + part[2 * 272 + tid] + part[3 * 272 + tid];
  atomicAdd(CtCadd + b * 256 + tid, v);
}

// ---------------------------------------------------------------------------
// Kernel B accumulate: qpart[ns][b][d][r] = sum_{n in slice} x[b,n,d]*coef[b,n,r]
// grid (16 d-tiles, 4 n-slices, 16 b) = 1024 blocks -> 16 waves/CU.
// ---------------------------------------------------------------------------
__global__ __launch_bounds__(256) void kernelBacc(
    const float* __restrict__ x, const float* __restrict__ coef,
    float* __restrict__ qpart)
{
  const int tid = threadIdx.x;
  const int dt = blockIdx.x, ns = blockIdx.y, b = blockIdx.z;
  const int d = dt * 256 + tid;
  const float* __restrict__ xp = x + ((size_t)(b * 512 + ns * 128)) * 4096 + d;
  const float* __restrict__ cp = coef + ((size_t)(b * 512 + ns * 128)) * 16;
  float acc[16];
#pragma unroll
  for (int r = 0; r < 16; ++r) acc[r] = 0.f;
#pragma unroll 4
  for (int n = 0; n < 128; ++n) {
    const float xv = xp[(size_t)n * 4096];          // coalesced b32
    const float* __restrict__ crow = cp + n * 16;   // wave-uniform -> s_load
#pragma unroll
    for (int r = 0; r < 16; ++r) acc[r] = fmaf(xv, crow[r], acc[r]);
  }
  float* __restrict__ qp = qpart + (((size_t)(ns * 16 + b)) * 4096 + d) * 16;
#pragma unroll
  for (int q = 0; q < 4; ++q)
    *(float4*)(qp + q * 4) = make_float4(acc[q * 4], acc[q * 4 + 1], acc[q * 4 + 2], acc[q * 4 + 3]);
}

// ---------------------------------------------------------------------------
// Kernel B finalize + fused BtB gram: Q = sum of 4 partials;
// bases *= Q / (bases CtC + eps); BtB += gram(bases')
// grid (16 d-tiles, 16 b); block 256 (thread = one d).
// ---------------------------------------------------------------------------
__global__ __launch_bounds__(256) void kernelBfin(
    const float* __restrict__ qpart, float* __restrict__ bases,
    const float* __restrict__ CtC, float* __restrict__ BtBadd)
{
  __shared__ __align__(16) float sm[256 * 20 + 4 * 272];
  const int tid = threadIdx.x;
  const int dt = blockIdx.x, b = blockIdx.y;
  const int d = dt * 256 + tid;
  float acc[16];
#pragma unroll
  for (int r = 0; r < 16; ++r) acc[r] = 0.f;
#pragma unroll
  for (int ns = 0; ns < 4; ++ns) {
    const float* __restrict__ qp = qpart + (((size_t)(ns * 16 + b)) * 4096 + d) * 16;
#pragma unroll
    for (int q = 0; q < 4; ++q) {
      float4 v = *(const float4*)(qp + q * 4);
      acc[q * 4 + 0] += v.x; acc[q * 4 + 1] += v.y; acc[q * 4 + 2] += v.z; acc[q * 4 + 3] += v.w;
    }
  }
  float* __restrict__ brow = bases + ((size_t)(b * 4096 + d)) * 16;
  float bv[16];
#pragma unroll
  for (int r = 0; r < 16; ++r) bv[r] = brow[r];
  const float* __restrict__ ctc = CtC + b * 256;
  float den[16];
#pragma unroll
  for (int r = 0; r < 16; ++r) den[r] = 0.f;
#pragma unroll
  for (int s2 = 0; s2 < 16; ++s2) {
    const float bs = bv[s2];
#pragma unroll
    for (int r = 0; r < 16; ++r) den[r] = fmaf(bs, ctc[s2 * 16 + r], den[r]);
  }
#pragma unroll
  for (int r = 0; r < 16; ++r) {
    float bn = bv[r] * acc[r] / (den[r] + EPS);
    brow[r] = bn;
    sm[tid * 20 + r] = bn;
  }
  __syncthreads();
  const int rq = tid & 3;
  const int s = (tid >> 2) & 15;
  const int g = tid >> 6;
  float a0 = 0.f, a1 = 0.f, a2 = 0.f, a3 = 0.f;
#pragma unroll 4
  for (int l = g * 64; l < g * 64 + 64; ++l) {
    float4 bq = *(const float4*)(&sm[l * 20 + rq * 4]);
    float cs = sm[l * 20 + s];
    a0 = fmaf(cs, bq.x, a0);
    a1 = fmaf(cs, bq.y, a1);
    a2 = fmaf(cs, bq.z, a2);
    a3 = fmaf(cs, bq.w, a3);
  }
  float* part = sm + 5120;
  *(float4*)(&part[g * 272 + s * 16 + rq * 4]) = make_float4(a0, a1, a2, a3);
  __syncthreads();
  float v = part[0 * 272 + tid] + part[1 * 272 + tid] + part[2 * 272 + tid] + part[3 * 272 + tid];
  atomicAdd(BtBadd + b * 256 + tid, v);
}

// ---------------------------------------------------------------------------
// Output: out[b,n,d] = sum_r bases[b,d,r]*coef[b,n,r]
// grid (4 d-tiles, 16 n-slices, 16 b) = 1024 blocks; thread owns 4 d (float4).
// ---------------------------------------------------------------------------
__global__ __launch_bounds__(256) void kernelOut(
    const float* __restrict__ bases, const float* __restrict__ coef,
    float* __restrict__ out)
{
  const int tid = threadIdx.x;
  const int dt = blockIdx.x, ns = blockIdx.y, b = blockIdx.z;
  const int d0 = dt * 1024 + tid * 4;
  float bv[4][16];
#pragma unroll
  for (int k = 0; k < 4; ++k) {
    const float* __restrict__ brow = bases + ((size_t)(b * 4096 + d0 + k)) * 16;
#pragma unroll
    for (int r = 0; r < 16; ++r) bv[k][r] = brow[r];
  }
  const float* __restrict__ cp = coef + ((size_t)(b * 512 + ns * 32)) * 16;
  float* __restrict__ op = out + ((size_t)(b * 512 + ns * 32)) * 4096 + d0;
#pragma unroll 4
  for (int n = 0; n < 32; ++n) {
    const float* __restrict__ crow = cp + n * 16;   // wave-uniform
    float v[4];
#pragma unroll
    for (int k = 0; k < 4; ++k) {
      float s = 0.f;
#pragma unroll
      for (int r = 0; r < 16; ++r) s = fmaf(bv[k][r], crow[r], s);
      v[k] = s;
    }
    *(float4*)(op + (size_t)n * 4096) = make_float4(v[0], v[1], v[2], v[3]);
  }
}

// ---------------------------------------------------------------------------
extern "C" void kernel_launch(void* const* d_in, const int* in_sizes, int n_in,
                              void* d_out, int out_size, void* d_ws, size_t ws_size,
                              hipStream_t stream) {
  const float* x = (const float*)d_in[0];         // 16*512*4096
  const float* bases_in = (const float*)d_in[1];  // 16*4096*16
  float* out = (float*)d_out;
  float* ws = (float*)d_ws;

  float* bases = ws;               // 1,048,576 floats
  float* coef  = bases + 1048576;  // 131,072
  float* P     = coef + 131072;    // 131,072
  float* btb0  = P + 131072;       // 4,096
  float* btb1  = btb0 + 4096;      // 4,096
  float* ctc   = btb1 + 4096;      // 4,096
  float* qpart = ctc + 4096;       // 4*16*4096*16 = 4,194,304
  float* btb[2] = {btb0, btb1};

  hipMemsetAsync(btb0, 0, 4096 * sizeof(float), stream);
  hipMemcpyAsync(bases, bases_in, 1048576 * sizeof(float),
                 hipMemcpyDeviceToDevice, stream);

  // init: P0 = X^T B0 (+ctc zero), coef = softmax(100*P0); BtB0 = gram(B0)
  kernelA<<<256, 512, 0, stream>>>(x, bases, P, coef, ctc, 1);
  kernelGram<<<dim3(16, 16), 256, 0, stream>>>(bases, btb0, 4096);

  for (int t = 0; t < 7; ++t) {
    if (t > 0) kernelA<<<256, 512, 0, stream>>>(x, bases, P, coef, ctc, 0);
    // coef update (reads BtB[t&1]) + fused CtC gram; zeros BtB[(t+1)&1]
    kernelCU<<<32, 256, 0, stream>>>(coef, P, btb[t & 1], btb[(t + 1) & 1], ctc);
    kernelBacc<<<dim3(16, 4, 16), 256, 0, stream>>>(x, coef, qpart);
    // bases update (reads CtC) + fused BtB gram into BtB[(t+1)&1]
    kernelBfin<<<dim3(16, 16), 256, 0, stream>>>(qpart, bases, ctc, btb[(t + 1) & 1]);
  }

  // final compute_coef with bases_7 / BtB[1], then reconstruct
  kernelA<<<256, 512, 0, stream>>>(x, bases, P, coef, ctc, 0);
  kernelCU<<<32, 256, 0, stream>>>(coef, P, btb[1], btb[0], ctc);
  kernelOut<<<dim3(4, 16, 16), 256, 0, stream>>>(bases, coef, out);
}

// Round 3
// 1019.218 us; speedup vs baseline: 1.0805x; 1.0805x over previous
//
#include <hip/hip_runtime.h>

#define EPS 1e-6f

// DPP helper: v += v rotated by CTRL within each 16-lane row (row_ror:n = 0x120+n)
template <int CTRL>
__device__ __forceinline__ float dpp_add(float v) {
  int moved = __builtin_amdgcn_update_dpp(0, __float_as_int(v), CTRL, 0xF, 0xF, false);
  return v + __int_as_float(moved);
}

// ---------------------------------------------------------------------------
// Kernel A: Ppart[h][b][n][r] = sum_{d in half h} x[b,n,d] * bases[b,d,r]
// grid (16 grp, 16 b, 2 h) = 512 blocks; block 512 = 8 waves.
// wave w: row-group rg = w&3 (8 rows), r-half rh = w>>2 (8 cols).
// acc[8][8] = 64 VGPRs/lane -> no spill (round-2 lesson: acc[8][16]=128 spilled).
// 40 KB LDS stages 512-d chunks of bases (stride 20, ~1.2x conflict measured).
// Blocks (grp==0, h==0) also zero CtC for this iteration's fused coef-gram.
// ---------------------------------------------------------------------------
__global__ __launch_bounds__(512, 4) void kernelA(
    const float* __restrict__ x, const float* __restrict__ bases,
    float* __restrict__ Ppart, float* __restrict__ CtC)
{
  __shared__ __align__(16) float lb[512 * 20];  // 40 KB
  const int tid = threadIdx.x;
  const int grp = blockIdx.x;
  const int b = blockIdx.y;
  const int h = blockIdx.z;
  if (h == 0 && grp == 0 && tid < 256) CtC[b * 256 + tid] = 0.0f;
  const int w = tid >> 6;
  const int lane = tid & 63;
  const int rg = w & 3;
  const int rh = w >> 2;
  const int n0 = grp * 32 + rg * 8;
  const float* __restrict__ xp = x + ((size_t)(b * 512 + n0)) * 4096 + h * 2048;
  const float4* __restrict__ srcf4 =
      (const float4*)(bases + ((size_t)(b * 4096 + h * 2048)) * 16);

  float acc[8][8];
#pragma unroll
  for (int i = 0; i < 8; ++i)
#pragma unroll
    for (int r = 0; r < 8; ++r) acc[i][r] = 0.0f;

  for (int c = 0; c < 4; ++c) {
    // stage bases rows [c*512, c*512+512) of this d-half: 2048 float4
#pragma unroll
    for (int k = 0; k < 4; ++k) {
      int idx = k * 512 + tid;
      int dl = idx >> 2, q = idx & 3;
      *(float4*)(&lb[dl * 20 + q * 4]) = srcf4[(c * 512 + dl) * 4 + q];
    }
    __syncthreads();
    const float* __restrict__ xpc = xp + c * 512;
#pragma unroll
    for (int j = 0; j < 8; ++j) {
      const int dl = j * 64 + lane;
      float4 b0 = *(const float4*)(&lb[dl * 20 + rh * 8]);
      float4 b1 = *(const float4*)(&lb[dl * 20 + rh * 8 + 4]);
      float xv[8];
#pragma unroll
      for (int i = 0; i < 8; ++i) xv[i] = xpc[(size_t)i * 4096 + dl];
#pragma unroll
      for (int i = 0; i < 8; ++i) {
        acc[i][0] = fmaf(xv[i], b0.x, acc[i][0]);
        acc[i][1] = fmaf(xv[i], b0.y, acc[i][1]);
        acc[i][2] = fmaf(xv[i], b0.z, acc[i][2]);
        acc[i][3] = fmaf(xv[i], b0.w, acc[i][3]);
        acc[i][4] = fmaf(xv[i], b1.x, acc[i][4]);
        acc[i][5] = fmaf(xv[i], b1.y, acc[i][5]);
        acc[i][6] = fmaf(xv[i], b1.z, acc[i][6]);
        acc[i][7] = fmaf(xv[i], b1.w, acc[i][7]);
      }
    }
    __syncthreads();
  }

  // butterfly-reduce each acc over the 64 lanes (all lanes end with the sum)
#pragma unroll
  for (int i = 0; i < 8; ++i)
#pragma unroll
    for (int r = 0; r < 8; ++r) {
      float v = acc[i][r];
      v = dpp_add<0x121>(v);
      v = dpp_add<0x122>(v);
      v = dpp_add<0x124>(v);
      v = dpp_add<0x128>(v);
      v += __shfl_xor(v, 16, 64);
      v += __shfl_xor(v, 32, 64);
      acc[i][r] = v;
    }

  if (lane == 0) {
    float* __restrict__ pp =
        Ppart + (((size_t)(h * 16 + b)) * 512 + n0) * 16 + rh * 8;
#pragma unroll
    for (int i = 0; i < 8; ++i) {
      *(float4*)(pp + i * 16) = make_float4(acc[i][0], acc[i][1], acc[i][2], acc[i][3]);
      *(float4*)(pp + i * 16 + 4) = make_float4(acc[i][4], acc[i][5], acc[i][6], acc[i][7]);
    }
  }
}

// ---------------------------------------------------------------------------
// Softmax init: coef[b,n,:] = softmax(100 * (Ppart0 + Ppart1)[b,n,:])
// grid 32 x 256; thread = one n row.
// ---------------------------------------------------------------------------
__global__ __launch_bounds__(256) void kernelSM(
    const float* __restrict__ Ppart, float* __restrict__ coef)
{
  const int gid = blockIdx.x * 256 + threadIdx.x;  // 0..8191
  const int b = gid >> 9, n = gid & 511;
  const float* __restrict__ p0 = Ppart + (((size_t)b) * 512 + n) * 16;
  const float* __restrict__ p1 = Ppart + (((size_t)(16 + b)) * 512 + n) * 16;
  float p[16];
#pragma unroll
  for (int r = 0; r < 16; ++r) p[r] = p0[r] + p1[r];
  float m = p[0];
#pragma unroll
  for (int r = 1; r < 16; ++r) m = fmaxf(m, p[r]);
  float e[16];
  float s = 0.0f;
#pragma unroll
  for (int r = 0; r < 16; ++r) { e[r] = __expf(100.0f * (p[r] - m)); s += e[r]; }
  float inv = 1.0f / s;
  float* __restrict__ crow = coef + (((size_t)b) * 512 + n) * 16;
#pragma unroll
  for (int r = 0; r < 16; ++r) crow[r] = e[r] * inv;
}

// ---------------------------------------------------------------------------
// Standalone gram (used once for BtB0): out[b,s*16+r] += sum_l M[.,r]*M[.,s]
// ---------------------------------------------------------------------------
__global__ __launch_bounds__(256) void kernelGram(
    const float* __restrict__ M, float* __restrict__ out, int L)
{
  __shared__ __align__(16) float sm[256 * 20];
  __shared__ __align__(16) float part[4 * 272];
  const int tid = threadIdx.x;
  const int b = blockIdx.y;
  const int sl = blockIdx.x;
  const float4* __restrict__ src = (const float4*)(M + ((size_t)b * L + (size_t)sl * 256) * 16);
#pragma unroll
  for (int k = 0; k < 4; ++k) {
    int idx = k * 256 + tid;
    int row = idx >> 2, q = idx & 3;
    *(float4*)(&sm[row * 20 + q * 4]) = src[idx];
  }
  __syncthreads();
  const int rq = tid & 3;
  const int s = (tid >> 2) & 15;
  const int g = tid >> 6;
  float a0 = 0.f, a1 = 0.f, a2 = 0.f, a3 = 0.f;
#pragma unroll 4
  for (int l = g * 64; l < g * 64 + 64; ++l) {
    float4 bv = *(const float4*)(&sm[l * 20 + rq * 4]);
    float cs = sm[l * 20 + s];
    a0 = fmaf(cs, bv.x, a0);
    a1 = fmaf(cs, bv.y, a1);
    a2 = fmaf(cs, bv.z, a2);
    a3 = fmaf(cs, bv.w, a3);
  }
  *(float4*)(&part[g * 272 + s * 16 + rq * 4]) = make_float4(a0, a1, a2, a3);
  __syncthreads();
  float v = part[0 * 272 + tid] + part[1 * 272 + tid] + part[2 * 272 + tid] + part[3 * 272 + tid];
  atomicAdd(out + b * 256 + tid, v);
}

// ---------------------------------------------------------------------------
// Coef update + fused CtC gram: coef *= (P0+P1) / (coef BtB + eps); CtC += gram
// grid 32; block 256 (thread = one n row). Also zeros BtBz.
// ---------------------------------------------------------------------------
__global__ __launch_bounds__(256) void kernelCU(
    float* __restrict__ coef, const float* __restrict__ Ppart,
    const float* __restrict__ BtBr, float* __restrict__ BtBz,
    float* __restrict__ CtCadd)
{
  __shared__ __align__(16) float sm[256 * 20 + 4 * 272];
  const int tid = threadIdx.x;
  BtBz[blockIdx.x * 128 + (tid & 127)] = 0.0f;
  const int b = blockIdx.x >> 1;
  const int n = ((blockIdx.x & 1) << 8) + tid;
  float* __restrict__ crow = coef + ((size_t)(b * 512 + n)) * 16;
  const float* __restrict__ p0 = Ppart + (((size_t)b) * 512 + n) * 16;
  const float* __restrict__ p1 = Ppart + (((size_t)(16 + b)) * 512 + n) * 16;
  const float* __restrict__ btb = BtBr + b * 256;
  float cv[16], den[16];
#pragma unroll
  for (int r = 0; r < 16; ++r) cv[r] = crow[r];
#pragma unroll
  for (int r = 0; r < 16; ++r) den[r] = 0.f;
#pragma unroll
  for (int s2 = 0; s2 < 16; ++s2) {
    const float bs = cv[s2];
#pragma unroll
    for (int r = 0; r < 16; ++r) den[r] = fmaf(bs, btb[s2 * 16 + r], den[r]);
  }
#pragma unroll
  for (int r = 0; r < 16; ++r) {
    float cn = cv[r] * (p0[r] + p1[r]) / (den[r] + EPS);
    crow[r] = cn;
    sm[tid * 20 + r] = cn;
  }
  __syncthreads();
  const int rq = tid & 3;
  const int s = (tid >> 2) & 15;
  const int g = tid >> 6;
  float a0 = 0.f, a1 = 0.f, a2 = 0.f, a3 = 0.f;
#pragma unroll 4
  for (int l = g * 64; l < g * 64 + 64; ++l) {
    float4 bv = *(const float4*)(&sm[l * 20 + rq * 4]);
    float cs = sm[l * 20 + s];
    a0 = fmaf(cs, bv.x, a0);
    a1 = fmaf(cs, bv.y, a1);
    a2 = fmaf(cs, bv.z, a2);
    a3 = fmaf(cs, bv.w, a3);
  }
  float* part = sm + 5120;
  *(float4*)(&part[g * 272 + s * 16 + rq * 4]) = make_float4(a0, a1, a2, a3);
  __syncthreads();
  float v = part[0 * 272 + tid] + part[1 * 272 + tid] + part[2 * 272 + tid] + part[3 * 272 + tid];
  atomicAdd(CtCadd + b * 256 + tid, v);
}

// ---------------------------------------------------------------------------
// Kernel B accumulate: qpart[ns][b][d][r] = sum_{n in slice} x[b,n,d]*coef[b,n,r]
// grid (16 d-tiles, 4 n-slices, 16 b) = 1024 blocks.
// ---------------------------------------------------------------------------
__global__ __launch_bounds__(256) void kernelBacc(
    const float* __restrict__ x, const float* __restrict__ coef,
    float* __restrict__ qpart)
{
  const int tid = threadIdx.x;
  const int dt = blockIdx.x, ns = blockIdx.y, b = blockIdx.z;
  const int d = dt * 256 + tid;
  const float* __restrict__ xp = x + ((size_t)(b * 512 + ns * 128)) * 4096 + d;
  const float* __restrict__ cp = coef + ((size_t)(b * 512 + ns * 128)) * 16;
  float acc[16];
#pragma unroll
  for (int r = 0; r < 16; ++r) acc[r] = 0.f;
#pragma unroll 4
  for (int n = 0; n < 128; ++n) {
    const float xv = xp[(size_t)n * 4096];
    const float* __restrict__ crow = cp + n * 16;   // wave-uniform -> s_load
#pragma unroll
    for (int r = 0; r < 16; ++r) acc[r] = fmaf(xv, crow[r], acc[r]);
  }
  float* __restrict__ qp = qpart + (((size_t)(ns * 16 + b)) * 4096 + d) * 16;
#pragma unroll
  for (int q = 0; q < 4; ++q)
    *(float4*)(qp + q * 4) = make_float4(acc[q * 4], acc[q * 4 + 1], acc[q * 4 + 2], acc[q * 4 + 3]);
}

// ---------------------------------------------------------------------------
// Kernel B finalize + fused BtB gram.
// grid (16 d-tiles, 16 b); block 256 (thread = one d).
// ---------------------------------------------------------------------------
__global__ __launch_bounds__(256) void kernelBfin(
    const float* __restrict__ qpart, float* __restrict__ bases,
    const float* __restrict__ CtC, float* __restrict__ BtBadd)
{
  __shared__ __align__(16) float sm[256 * 20 + 4 * 272];
  const int tid = threadIdx.x;
  const int dt = blockIdx.x, b = blockIdx.y;
  const int d = dt * 256 + tid;
  float acc[16];
#pragma unroll
  for (int r = 0; r < 16; ++r) acc[r] = 0.f;
#pragma unroll
  for (int ns = 0; ns < 4; ++ns) {
    const float* __restrict__ qp = qpart + (((size_t)(ns * 16 + b)) * 4096 + d) * 16;
#pragma unroll
    for (int q = 0; q < 4; ++q) {
      float4 v = *(const float4*)(qp + q * 4);
      acc[q * 4 + 0] += v.x; acc[q * 4 + 1] += v.y; acc[q * 4 + 2] += v.z; acc[q * 4 + 3] += v.w;
    }
  }
  float* __restrict__ brow = bases + ((size_t)(b * 4096 + d)) * 16;
  float bv[16];
#pragma unroll
  for (int r = 0; r < 16; ++r) bv[r] = brow[r];
  const float* __restrict__ ctc = CtC + b * 256;
  float den[16];
#pragma unroll
  for (int r = 0; r < 16; ++r) den[r] = 0.f;
#pragma unroll
  for (int s2 = 0; s2 < 16; ++s2) {
    const float bs = bv[s2];
#pragma unroll
    for (int r = 0; r < 16; ++r) den[r] = fmaf(bs, ctc[s2 * 16 + r], den[r]);
  }
#pragma unroll
  for (int r = 0; r < 16; ++r) {
    float bn = bv[r] * acc[r] / (den[r] + EPS);
    brow[r] = bn;
    sm[tid * 20 + r] = bn;
  }
  __syncthreads();
  const int rq = tid & 3;
  const int s = (tid >> 2) & 15;
  const int g = tid >> 6;
  float a0 = 0.f, a1 = 0.f, a2 = 0.f, a3 = 0.f;
#pragma unroll 4
  for (int l = g * 64; l < g * 64 + 64; ++l) {
    float4 bq = *(const float4*)(&sm[l * 20 + rq * 4]);
    float cs = sm[l * 20 + s];
    a0 = fmaf(cs, bq.x, a0);
    a1 = fmaf(cs, bq.y, a1);
    a2 = fmaf(cs, bq.z, a2);
    a3 = fmaf(cs, bq.w, a3);
  }
  float* part = sm + 5120;
  *(float4*)(&part[g * 272 + s * 16 + rq * 4]) = make_float4(a0, a1, a2, a3);
  __syncthreads();
  float v = part[0 * 272 + tid] + part[1 * 272 + tid] + part[2 * 272 + tid] + part[3 * 272 + tid];
  atomicAdd(BtBadd + b * 256 + tid, v);
}

// ---------------------------------------------------------------------------
// Output: out[b,n,d] = sum_r bases[b,d,r]*coef[b,n,r]
// grid (4 d-tiles, 16 n-slices, 16 b); thread owns 4 d (float4 stores).
// ---------------------------------------------------------------------------
__global__ __launch_bounds__(256) void kernelOut(
    const float* __restrict__ bases, const float* __restrict__ coef,
    float* __restrict__ out)
{
  const int tid = threadIdx.x;
  const int dt = blockIdx.x, ns = blockIdx.y, b = blockIdx.z;
  const int d0 = dt * 1024 + tid * 4;
  float bv[4][16];
#pragma unroll
  for (int k = 0; k < 4; ++k) {
    const float* __restrict__ brow = bases + ((size_t)(b * 4096 + d0 + k)) * 16;
#pragma unroll
    for (int r = 0; r < 16; ++r) bv[k][r] = brow[r];
  }
  const float* __restrict__ cp = coef + ((size_t)(b * 512 + ns * 32)) * 16;
  float* __restrict__ op = out + ((size_t)(b * 512 + ns * 32)) * 4096 + d0;
#pragma unroll 4
  for (int n = 0; n < 32; ++n) {
    const float* __restrict__ crow = cp + n * 16;
    float v[4];
#pragma unroll
    for (int k = 0; k < 4; ++k) {
      float s = 0.f;
#pragma unroll
      for (int r = 0; r < 16; ++r) s = fmaf(bv[k][r], crow[r], s);
      v[k] = s;
    }
    *(float4*)(op + (size_t)n * 4096) = make_float4(v[0], v[1], v[2], v[3]);
  }
}

// ---------------------------------------------------------------------------
extern "C" void kernel_launch(void* const* d_in, const int* in_sizes, int n_in,
                              void* d_out, int out_size, void* d_ws, size_t ws_size,
                              hipStream_t stream) {
  const float* x = (const float*)d_in[0];         // 16*512*4096
  const float* bases_in = (const float*)d_in[1];  // 16*4096*16
  float* out = (float*)d_out;
  float* ws = (float*)d_ws;

  float* bases = ws;               // 1,048,576 floats
  float* coef  = bases + 1048576;  // 131,072
  float* Ppart = coef + 131072;    // 262,144 (2 d-half partials)
  float* btb0  = Ppart + 262144;   // 4,096
  float* btb1  = btb0 + 4096;      // 4,096
  float* ctc   = btb1 + 4096;      // 4,096
  float* qpart = ctc + 4096;       // 4*16*4096*16 = 4,194,304
  float* btb[2] = {btb0, btb1};

  hipMemsetAsync(btb0, 0, 4096 * sizeof(float), stream);
  hipMemcpyAsync(bases, bases_in, 1048576 * sizeof(float),
                 hipMemcpyDeviceToDevice, stream);

  // init: Ppart = X^T B0 (+ctc zero), coef = softmax(100*P); BtB0 = gram(B0)
  kernelA<<<dim3(16, 16, 2), 512, 0, stream>>>(x, bases, Ppart, ctc);
  kernelSM<<<32, 256, 0, stream>>>(Ppart, coef);
  kernelGram<<<dim3(16, 16), 256, 0, stream>>>(bases, btb0, 4096);

  for (int t = 0; t < 7; ++t) {
    if (t > 0) kernelA<<<dim3(16, 16, 2), 512, 0, stream>>>(x, bases, Ppart, ctc);
    kernelCU<<<32, 256, 0, stream>>>(coef, Ppart, btb[t & 1], btb[(t + 1) & 1], ctc);
    kernelBacc<<<dim3(16, 4, 16), 256, 0, stream>>>(x, coef, qpart);
    kernelBfin<<<dim3(16, 16), 256, 0, stream>>>(qpart, bases, ctc, btb[(t + 1) & 1]);
  }

  // final compute_coef with bases_7 / BtB[1], then reconstruct
  kernelA<<<dim3(16, 16, 2), 512, 0, stream>>>(x, bases, Ppart, ctc);
  kernelCU<<<32, 256, 0, stream>>>(coef, Ppart, btb[1], btb[0], ctc);
  kernelOut<<<dim3(4, 16, 16), 256, 0, stream>>>(bases, coef, out);
}